// Round 15
// baseline (112.423 us; speedup 1.0000x reference)
//
#include <hip/hip_runtime.h>
#include <math.h>

#define DD 128
#define NSPLIT 24
#define NBINS 512
#define SHIFT 10.0f
#define L2E_T 14.4269504089f   // 10 * log2(e)

typedef _Float16 f16x8 __attribute__((ext_vector_type(8)));
typedef _Float16 f16x2 __attribute__((ext_vector_type(2)));
typedef float f32x4 __attribute__((ext_vector_type(4)));

// guard-free 2^x: args are in [-29, 0], no denorm/overflow concerns
__device__ __forceinline__ float ex2(float x) {
#if __has_builtin(__builtin_amdgcn_exp2f)
    return __builtin_amdgcn_exp2f(x);
#else
    return exp2f(x);
#endif
}

// ---- tiny zero: hist (512 ints) + d_out; 1 block, ~1us ----
__global__ __launch_bounds__(256)
void zero_kernel(int* __restrict__ hist, float* __restrict__ out)
{
    hist[threadIdx.x] = 0;
    hist[256 + threadIdx.x] = 0;
    if (threadIdx.x == 0) out[0] = 0.f;
}

// ---- normalize rows -> f16, labels, histogram ----
__global__ __launch_bounds__(256)
void norm_kernel(const float* __restrict__ f, const int* __restrict__ labels,
                 _Float16* __restrict__ fh, int* __restrict__ labm,
                 int* __restrict__ hist, int M, int nrep)
{
    int gw = (blockIdx.x * 256 + threadIdx.x) >> 6;   // one wave per row
    int lane = threadIdx.x & 63;
    if (gw >= M) return;
    float2 v = *reinterpret_cast<const float2*>(&f[(size_t)gw * DD + lane * 2]);
    float ss = v.x * v.x + v.y * v.y;
    #pragma unroll
    for (int m = 1; m < 64; m <<= 1) ss += __shfl_xor(ss, m);
    float inv = 1.0f / fmaxf(sqrtf(ss), 1e-12f);
    f16x2 h; h[0] = (_Float16)(v.x * inv); h[1] = (_Float16)(v.y * inv);
    *reinterpret_cast<f16x2*>(&fh[(size_t)gw * DD + lane * 2]) = h;
    if (lane == 0) {
        int lb = labels[gw / nrep];
        labm[gw] = lb;
        if ((gw % nrep) == 0) atomicAdd(&hist[lb], nrep);  // one atomic per sample
    }
}

// ---- main: f16 MFMA stream with LDS-staged j-batches (plain HIP) ----
// R12 compute core (4 waves/block, 64 i-rows register-resident, (256,3),
// raw v_exp_f32, grid 32x24 = 3 blocks/CU). New: j-subtiles staged into
// double-buffered LDS in 4-subtile batches (2 x 16KB), cooperatively by all
// 256 threads -> each wave's per-phase global loads (4x redundant across
// waves, L1/L2-latency exposed every phase) become swizzled ds_read_b128.
// Staging loads for batch t+1 issue BEFORE compute of batch t (a whole
// batch of compute covers global latency); plain __syncthreads only.
// Swizzle chunk ^= row&7: unswizzled, the 16 rowsel-lanes of each grp hit
// the same 4 banks (16-way conflict). Self-pair included; final subtracts.
__global__ __launch_bounds__(256, 3)
void supcon_main(const _Float16* __restrict__ fh, const int* __restrict__ labm,
                 float* __restrict__ Epart, float* __restrict__ Ppart,
                 int M, int nsub_total)
{
    __shared__ float4 jbuf[2][1024];   // 2 x (4 subtiles x 64 rows x 16 chunks)
    __shared__ int    jlab[2][64];

    const int tid = threadIdx.x;
    const int lane = tid & 63;
    const int w = tid >> 6;
    const int ibase = blockIdx.x * 256 + w * 64;
    const int rowsel = lane & 15;
    const int grp = lane >> 4;
    const int ksel = grp * 8;      // f16 k-offset within a 32-wide K step

    // register-resident Fi fragments: 4 subtiles x 4 K-steps = 64 regs
    f16x8 bfr[4][4];
    #pragma unroll
    for (int t = 0; t < 4; ++t)
        #pragma unroll
        for (int kk = 0; kk < 4; ++kk)
            bfr[t][kk] = *reinterpret_cast<const f16x8*>(
                &fh[(size_t)(ibase + t * 16 + rowsel) * DD + kk * 32 + ksel]);

    int li[4];
    #pragma unroll
    for (int t = 0; t < 4; ++t) li[t] = labm[ibase + t * 16 + rowsel];

    float esum[4] = {0.f, 0.f, 0.f, 0.f};
    float psum[4] = {0.f, 0.f, 0.f, 0.f};

    // uneven subtile range for this j-split
    const int base = nsub_total / NSPLIT, rem = nsub_total % NSPLIT;
    const int by = blockIdx.y;
    const int s0 = by * base + (by < rem ? by : rem);
    const int send = s0 + base + (by < rem ? 1 : 0);
    const int nsub = send - s0;          // 21 or 22
    const int nb = (nsub + 3) >> 2;      // 4-subtile batches
    const int rowmax = nsub_total * 16 - 1;

    // staging geometry: 4 float4 chunks per thread per batch
    int srow[4], sc4[4];
    #pragma unroll
    for (int p = 0; p < 4; ++p) {
        int g = p * 256 + tid;
        srow[p] = g >> 4;
        sc4[p] = g & 15;
    }

    float4 R[4];
    int labR = 0;

#define STAGE_LOAD(tt) { \
    const int rb = (s0 + (tt) * 4) * 16; \
    _Pragma("unroll") for (int p = 0; p < 4; ++p) { \
        int rr = rb + srow[p]; if (rr > rowmax) rr = rowmax; \
        R[p] = *reinterpret_cast<const float4*>(&fh[(size_t)rr * DD + sc4[p] * 8]); } \
    if (tid < 64) { int rr = rb + tid; if (rr > rowmax) rr = rowmax; labR = labm[rr]; } }

#define STAGE_WRITE(bb) { \
    _Pragma("unroll") for (int p = 0; p < 4; ++p) { \
        int slot = srow[p] * 16 + (sc4[p] ^ (srow[p] & 7)); \
        jbuf[bb][slot] = R[p]; } \
    if (tid < 64) jlab[bb][tid] = labR; }

#define MFMA16(A, c0, c1, c2, c3) { \
    _Pragma("unroll") for (int kk = 0; kk < 4; ++kk) { \
        c0 = __builtin_amdgcn_mfma_f32_16x16x32_f16(A[kk], bfr[0][kk], c0, 0, 0, 0); \
        c1 = __builtin_amdgcn_mfma_f32_16x16x32_f16(A[kk], bfr[1][kk], c1, 0, 0, 0); \
        c2 = __builtin_amdgcn_mfma_f32_16x16x32_f16(A[kk], bfr[2][kk], c2, 0, 0, 0); \
        c3 = __builtin_amdgcn_mfma_f32_16x16x32_f16(A[kk], bfr[3][kk], c3, 0, 0, 0); } }

#define EPI1(t, cc, L) { \
    esum[t] += (ex2(__builtin_fmaf(cc[0], L2E_T, -L2E_T)) \
              + ex2(__builtin_fmaf(cc[1], L2E_T, -L2E_T))) \
             + (ex2(__builtin_fmaf(cc[2], L2E_T, -L2E_T)) \
              + ex2(__builtin_fmaf(cc[3], L2E_T, -L2E_T))); \
    float p0 = (L.x == li[t]) ? cc[0] : 0.f; \
    float p1 = (L.y == li[t]) ? cc[1] : 0.f; \
    float p2 = (L.z == li[t]) ? cc[2] : 0.f; \
    float p3 = (L.w == li[t]) ? cc[3] : 0.f; \
    psum[t] += (p0 + p1) + (p2 + p3); }

#define EPI4(c0, c1, c2, c3, L) { \
    EPI1(0, c0, L); EPI1(1, c1, L); EPI1(2, c2, L); EPI1(3, c3, L); }

#define COMPUTE(bb, tt) { \
    const int nv = ((tt) == nb - 1) ? (nsub - (nb - 1) * 4) : 4; \
    _Pragma("unroll") for (int k = 0; k < 4; ++k) { \
        if (k < nv) { \
            f16x8 af[4]; \
            const int row = k * 16 + rowsel; \
            _Pragma("unroll") for (int kk = 0; kk < 4; ++kk) { \
                int slot = row * 16 + ((grp + kk * 4) ^ (row & 7)); \
                af[kk] = *reinterpret_cast<const f16x8*>(&jbuf[bb][slot]); } \
            const int4 lj = *reinterpret_cast<const int4*>(&jlab[bb][k * 16 + grp * 4]); \
            f32x4 c0 = {0,0,0,0}, c1 = {0,0,0,0}, c2 = {0,0,0,0}, c3 = {0,0,0,0}; \
            MFMA16(af, c0, c1, c2, c3); \
            EPI4(c0, c1, c2, c3, lj); } } }

    STAGE_LOAD(0);
    STAGE_WRITE(0);
    __syncthreads();
    for (int t = 0; t < nb; ++t) {
        if (t + 1 < nb) STAGE_LOAD(t + 1);   // latency hidden under COMPUTE
        COMPUTE(t & 1, t);
        __syncthreads();                     // all reads of buf[t&1] done
        if (t + 1 < nb) {
            STAGE_WRITE((t + 1) & 1);        // overwrites buffer read at t-1
            __syncthreads();                 // visible before t+1's compute
        }
    }
#undef STAGE_LOAD
#undef STAGE_WRITE
#undef MFMA16
#undef EPI1
#undef EPI4
#undef COMPUTE

    // fold lane groups (bits 4,5 = different j rows of the same i)
    #pragma unroll
    for (int t = 0; t < 4; ++t) {
        float e = esum[t], p = psum[t];
        e += __shfl_xor(e, 16); e += __shfl_xor(e, 32);
        p += __shfl_xor(p, 16); p += __shfl_xor(p, 32);
        if (lane < 16) {
            size_t o = (size_t)by * M + ibase + t * 16 + lane;
            Epart[o] = e;
            Ppart[o] = p;
        }
    }
}

// ---- per-row loss term: one thread per row, coalesced partial reads,
// block-reduce, one atomic per block ----
__global__ __launch_bounds__(256)
void final_fused(const _Float16* __restrict__ fh, const float* __restrict__ Epart,
                 const float* __restrict__ Ppart, const int* __restrict__ labm,
                 const int* __restrict__ hist, float* __restrict__ out, int M)
{
    __shared__ float red[4];
    const int i = blockIdx.x * 256 + threadIdx.x;   // one row per thread
    float aii = 0.f;
    const f16x8* fr = reinterpret_cast<const f16x8*>(&fh[(size_t)i * DD]);
    #pragma unroll
    for (int k = 0; k < 16; ++k) {
        f16x8 hv = fr[k];
        #pragma unroll
        for (int e = 0; e < 8; ++e) {
            float x = (float)hv[e];
            aii = __builtin_fmaf(x, x, aii);
        }
    }
    float E = 0.f, P = 0.f;
    #pragma unroll
    for (int k = 0; k < NSPLIT; ++k) {
        E += Epart[(size_t)k * M + i];
        P += Ppart[(size_t)k * M + i];
    }
    int lb = labm[i];
    float cnt = (float)(hist[lb] - 1);
    E -= ex2(__builtin_fmaf(aii, L2E_T, -L2E_T));   // drop self exp
    float term = (SHIFT + logf(E)) - SHIFT * (P - aii) / cnt;

    #pragma unroll
    for (int m = 1; m < 64; m <<= 1) term += __shfl_xor(term, m);
    int lane = threadIdx.x & 63, wv = threadIdx.x >> 6;
    if (lane == 0) red[wv] = term;
    __syncthreads();
    if (threadIdx.x == 0)
        atomicAdd(out, (red[0] + red[1] + red[2] + red[3]) / (float)M);
}

extern "C" void kernel_launch(void* const* d_in, const int* in_sizes, int n_in,
                              void* d_out, int out_size, void* d_ws, size_t ws_size,
                              hipStream_t stream)
{
    const float* feats = (const float*)d_in[0];
    const int* labels = (const int*)d_in[1];
    const int Bn = in_sizes[1];
    const int M = in_sizes[0] / DD;    // 8192
    const int nrep = M / Bn;           // 2

    char* ws = (char*)d_ws;
    _Float16* fh = (_Float16*)ws;
    size_t off = (size_t)M * DD * sizeof(_Float16);
    int* labm = (int*)(ws + off); off += (size_t)M * sizeof(int);
    int* hist = (int*)(ws + off); off += (size_t)NBINS * sizeof(int);
    off = (off + 255) & ~(size_t)255;
    float* Epart = (float*)(ws + off); off += (size_t)NSPLIT * M * sizeof(float);
    float* Ppart = (float*)(ws + off); off += (size_t)NSPLIT * M * sizeof(float);

    zero_kernel<<<1, 256, 0, stream>>>(hist, (float*)d_out);

    norm_kernel<<<M / 4, 256, 0, stream>>>(feats, labels, fh, labm, hist, M, nrep);

    const int nsub_total = M / 16;     // 512 j-subtiles split unevenly over 24
    dim3 grid(M / 256, NSPLIT);        // 32 x 24 = 768 blocks (3/CU, 1 round)
    supcon_main<<<grid, 256, 0, stream>>>(fh, labm, Epart, Ppart, M, nsub_total);

    final_fused<<<M / 256, 256, 0, stream>>>(fh, Epart, Ppart, labm, hist,
                                             (float*)d_out, M);
}

// Round 16
// 54.713 us; speedup vs baseline: 2.0548x; 2.0548x over previous
//
#include <hip/hip_runtime.h>
#include <math.h>

#define DD 128
#define NSPLIT 24
#define NBINS 512
#define SHIFT 10.0f
#define L2E_T 14.4269504089f   // 10 * log2(e)

#define AS1 __attribute__((address_space(1)))
#define AS3 __attribute__((address_space(3)))

typedef _Float16 f16x8 __attribute__((ext_vector_type(8)));
typedef _Float16 f16x2 __attribute__((ext_vector_type(2)));
typedef float f32x4 __attribute__((ext_vector_type(4)));

// guard-free 2^x: args are in [-29, 0], no denorm/overflow concerns
__device__ __forceinline__ float ex2(float x) {
#if __has_builtin(__builtin_amdgcn_exp2f)
    return __builtin_amdgcn_exp2f(x);
#else
    return exp2f(x);
#endif
}

// ---- tiny zero: hist (512 ints) + d_out; 1 block, ~1us ----
__global__ __launch_bounds__(256)
void zero_kernel(int* __restrict__ hist, float* __restrict__ out)
{
    hist[threadIdx.x] = 0;
    hist[256 + threadIdx.x] = 0;
    if (threadIdx.x == 0) out[0] = 0.f;
}

// ---- normalize rows -> f16, labels, histogram ----
__global__ __launch_bounds__(256)
void norm_kernel(const float* __restrict__ f, const int* __restrict__ labels,
                 _Float16* __restrict__ fh, int* __restrict__ labm,
                 int* __restrict__ hist, int M, int nrep)
{
    int gw = (blockIdx.x * 256 + threadIdx.x) >> 6;   // one wave per row
    int lane = threadIdx.x & 63;
    if (gw >= M) return;
    float2 v = *reinterpret_cast<const float2*>(&f[(size_t)gw * DD + lane * 2]);
    float ss = v.x * v.x + v.y * v.y;
    #pragma unroll
    for (int m = 1; m < 64; m <<= 1) ss += __shfl_xor(ss, m);
    float inv = 1.0f / fmaxf(sqrtf(ss), 1e-12f);
    f16x2 h; h[0] = (_Float16)(v.x * inv); h[1] = (_Float16)(v.y * inv);
    *reinterpret_cast<f16x2*>(&fh[(size_t)gw * DD + lane * 2]) = h;
    if (lane == 0) {
        int lb = labels[gw / nrep];
        labm[gw] = lb;
        if ((gw % nrep) == 0) atomicAdd(&hist[lb], nrep);  // one atomic per sample
    }
}

// ---- main: f16 MFMA stream; j-batches staged via global_load_lds ----
// R12 compute core (4 waves/block, 64 i-rows register-resident, (256,3),
// raw v_exp_f32, 32x24 grid = 3 blocks/CU). Staging: 4-subtile batches
// (64 rows x 256B = 16KB) DMA'd straight to double-buffered LDS with
// __builtin_amdgcn_global_load_lds (16B/lane, NO VGPR round-trip -- the
// reg-staged variants R5/R14/R15 all spilled). Layout per rule-21:
// linear LDS dest + inverse-swizzled per-lane GLOBAL source + the same
// XOR swizzle on ds_read (involution), so the 16-rowsel-lane read is
// 2-way bank = free. One __syncthreads per batch, placed AFTER a full
// batch of compute has covered the in-flight loads (m97 pattern).
// Self-pair included; final kernel subtracts it exactly.
__global__ __launch_bounds__(256, 3)
void supcon_main(const _Float16* __restrict__ fh, const int* __restrict__ labm,
                 float* __restrict__ Epart, float* __restrict__ Ppart,
                 int M, int nsub_total)
{
    __shared__ float4 jbuf[2][1024];   // 2 x (64 rows x 16 chunks of 16B)

    const int tid = threadIdx.x;
    const int lane = tid & 63;
    const int w = tid >> 6;
    const int ibase = blockIdx.x * 256 + w * 64;
    const int rowsel = lane & 15;
    const int grp = lane >> 4;
    const int ksel = grp * 8;      // f16 k-offset within a 32-wide K step

    // register-resident Fi fragments: 4 subtiles x 4 K-steps = 64 regs
    f16x8 bfr[4][4];
    #pragma unroll
    for (int t = 0; t < 4; ++t)
        #pragma unroll
        for (int kk = 0; kk < 4; ++kk)
            bfr[t][kk] = *reinterpret_cast<const f16x8*>(
                &fh[(size_t)(ibase + t * 16 + rowsel) * DD + kk * 32 + ksel]);

    int li[4];
    #pragma unroll
    for (int t = 0; t < 4; ++t) li[t] = labm[ibase + t * 16 + rowsel];

    float esum[4] = {0.f, 0.f, 0.f, 0.f};
    float psum[4] = {0.f, 0.f, 0.f, 0.f};

    // uneven subtile range for this j-split
    const int base = nsub_total / NSPLIT, rem = nsub_total % NSPLIT;
    const int by = blockIdx.y;
    const int s0 = by * base + (by < rem ? by : rem);
    const int send = s0 + base + (by < rem ? 1 : 0);
    const int nsub = send - s0;          // 21 or 22
    const int nb = (nsub + 3) >> 2;      // 4-subtile batches
    const int rowmax = nsub_total * 16 - 1;

    // staging geometry: wave w, instr p covers LDS slots [(p*4+w)*64, +64);
    // slot s holds global chunk (row = s>>4, c = (s&15) ^ ((s>>4)&7)) so the
    // linear DMA write produces the swizzled layout the reader expects.
    int srow[4], scol[4];
    #pragma unroll
    for (int p = 0; p < 4; ++p) {
        int s = (p * 4 + w) * 64 + lane;
        srow[p] = s >> 4;                          // batch-local row 0..63
        scol[p] = ((s & 15) ^ ((s >> 4) & 7)) * 8; // f16 offset of source chunk
    }

#define STAGE(bb, tt) { \
    const int rb = (s0 + (tt) * 4) * 16; \
    _Pragma("unroll") for (int p = 0; p < 4; ++p) { \
        int rr = rb + srow[p]; if (rr > rowmax) rr = rowmax; \
        const _Float16* gsrc = fh + (size_t)rr * DD + scol[p]; \
        __builtin_amdgcn_global_load_lds((const AS1 void*)gsrc, \
            (AS3 void*)&jbuf[bb][(p * 4 + w) * 64], 16, 0, 0); } }

#define MFMA16(A, c0, c1, c2, c3) { \
    _Pragma("unroll") for (int kk = 0; kk < 4; ++kk) { \
        c0 = __builtin_amdgcn_mfma_f32_16x16x32_f16(A[kk], bfr[0][kk], c0, 0, 0, 0); \
        c1 = __builtin_amdgcn_mfma_f32_16x16x32_f16(A[kk], bfr[1][kk], c1, 0, 0, 0); \
        c2 = __builtin_amdgcn_mfma_f32_16x16x32_f16(A[kk], bfr[2][kk], c2, 0, 0, 0); \
        c3 = __builtin_amdgcn_mfma_f32_16x16x32_f16(A[kk], bfr[3][kk], c3, 0, 0, 0); } }

#define EPI1(t, cc, L) { \
    esum[t] += (ex2(__builtin_fmaf(cc[0], L2E_T, -L2E_T)) \
              + ex2(__builtin_fmaf(cc[1], L2E_T, -L2E_T))) \
             + (ex2(__builtin_fmaf(cc[2], L2E_T, -L2E_T)) \
              + ex2(__builtin_fmaf(cc[3], L2E_T, -L2E_T))); \
    float p0 = (L.x == li[t]) ? cc[0] : 0.f; \
    float p1 = (L.y == li[t]) ? cc[1] : 0.f; \
    float p2 = (L.z == li[t]) ? cc[2] : 0.f; \
    float p3 = (L.w == li[t]) ? cc[3] : 0.f; \
    psum[t] += (p0 + p1) + (p2 + p3); }

#define EPI4(c0, c1, c2, c3, L) { \
    EPI1(0, c0, L); EPI1(1, c1, L); EPI1(2, c2, L); EPI1(3, c3, L); }

// read: af[kk] = chunk (row = k*16+rowsel, cread = kk*4+grp) at slot
// row*16 + (cread ^ (rowsel&7))  [row&7 == rowsel&7 since k*16 % 8 == 0]
#define COMPUTE(bb, tt) { \
    const int nv = ((tt) == nb - 1) ? (nsub - (nb - 1) * 4) : 4; \
    _Pragma("unroll") for (int k = 0; k < 4; ++k) { \
        if (k < nv) { \
            f16x8 af[4]; \
            _Pragma("unroll") for (int kk = 0; kk < 4; ++kk) { \
                int slot = (k * 16 + rowsel) * 16 + ((kk * 4 + grp) ^ (rowsel & 7)); \
                af[kk] = *reinterpret_cast<const f16x8*>(&jbuf[bb][slot]); } \
            const int4 lj = *reinterpret_cast<const int4*>( \
                &labm[(s0 + (tt) * 4 + k) * 16 + grp * 4]); \
            f32x4 c0 = {0,0,0,0}, c1 = {0,0,0,0}, c2 = {0,0,0,0}, c3 = {0,0,0,0}; \
            MFMA16(af, c0, c1, c2, c3); \
            EPI4(c0, c1, c2, c3, lj); } } }

    STAGE(0, 0);
    __syncthreads();                         // drain batch-0 DMA + barrier
    for (int t = 0; t < nb; ++t) {
        if (t + 1 < nb) STAGE((t + 1) & 1, t + 1);   // DMA next batch
        COMPUTE(t & 1, t);                   // covers the DMA latency
        __syncthreads();                     // drain DMA + readers done
    }
#undef STAGE
#undef MFMA16
#undef EPI1
#undef EPI4
#undef COMPUTE

    // fold lane groups (bits 4,5 = different j rows of the same i)
    #pragma unroll
    for (int t = 0; t < 4; ++t) {
        float e = esum[t], p = psum[t];
        e += __shfl_xor(e, 16); e += __shfl_xor(e, 32);
        p += __shfl_xor(p, 16); p += __shfl_xor(p, 32);
        if (lane < 16) {
            size_t o = (size_t)by * M + ibase + t * 16 + lane;
            Epart[o] = e;
            Ppart[o] = p;
        }
    }
}

// ---- per-row loss term: one thread per row, coalesced partial reads,
// block-reduce, one atomic per block ----
__global__ __launch_bounds__(256)
void final_fused(const _Float16* __restrict__ fh, const float* __restrict__ Epart,
                 const float* __restrict__ Ppart, const int* __restrict__ labm,
                 const int* __restrict__ hist, float* __restrict__ out, int M)
{
    __shared__ float red[4];
    const int i = blockIdx.x * 256 + threadIdx.x;   // one row per thread
    float aii = 0.f;
    const f16x8* fr = reinterpret_cast<const f16x8*>(&fh[(size_t)i * DD]);
    #pragma unroll
    for (int k = 0; k < 16; ++k) {
        f16x8 hv = fr[k];
        #pragma unroll
        for (int e = 0; e < 8; ++e) {
            float x = (float)hv[e];
            aii = __builtin_fmaf(x, x, aii);
        }
    }
    float E = 0.f, P = 0.f;
    #pragma unroll
    for (int k = 0; k < NSPLIT; ++k) {
        E += Epart[(size_t)k * M + i];
        P += Ppart[(size_t)k * M + i];
    }
    int lb = labm[i];
    float cnt = (float)(hist[lb] - 1);
    E -= ex2(__builtin_fmaf(aii, L2E_T, -L2E_T));   // drop self exp
    float term = (SHIFT + logf(E)) - SHIFT * (P - aii) / cnt;

    #pragma unroll
    for (int m = 1; m < 64; m <<= 1) term += __shfl_xor(term, m);
    int lane = threadIdx.x & 63, wv = threadIdx.x >> 6;
    if (lane == 0) red[wv] = term;
    __syncthreads();
    if (threadIdx.x == 0)
        atomicAdd(out, (red[0] + red[1] + red[2] + red[3]) / (float)M);
}

extern "C" void kernel_launch(void* const* d_in, const int* in_sizes, int n_in,
                              void* d_out, int out_size, void* d_ws, size_t ws_size,
                              hipStream_t stream)
{
    const float* feats = (const float*)d_in[0];
    const int* labels = (const int*)d_in[1];
    const int Bn = in_sizes[1];
    const int M = in_sizes[0] / DD;    // 8192
    const int nrep = M / Bn;           // 2

    char* ws = (char*)d_ws;
    _Float16* fh = (_Float16*)ws;
    size_t off = (size_t)M * DD * sizeof(_Float16);
    int* labm = (int*)(ws + off); off += (size_t)M * sizeof(int);
    int* hist = (int*)(ws + off); off += (size_t)NBINS * sizeof(int);
    off = (off + 255) & ~(size_t)255;
    float* Epart = (float*)(ws + off); off += (size_t)NSPLIT * M * sizeof(float);
    float* Ppart = (float*)(ws + off); off += (size_t)NSPLIT * M * sizeof(float);

    zero_kernel<<<1, 256, 0, stream>>>(hist, (float*)d_out);

    norm_kernel<<<M / 4, 256, 0, stream>>>(feats, labels, fh, labm, hist, M, nrep);

    const int nsub_total = M / 16;     // 512 j-subtiles split unevenly over 24
    dim3 grid(M / 256, NSPLIT);        // 32 x 24 = 768 blocks (3/CU, 1 round)
    supcon_main<<<grid, 256, 0, stream>>>(fh, labm, Epart, Ppart, M, nsub_total);

    final_fused<<<M / 256, 256, 0, stream>>>(fh, Epart, Ppart, labm, hist,
                                             (float*)d_out, M);
}

// Round 17
// 49.006 us; speedup vs baseline: 2.2940x; 1.1164x over previous
//
#include <hip/hip_runtime.h>
#include <math.h>

#define DD 128
#define NSPLIT 24
#define NBINS 512
#define SHIFT 10.0f
#define L2E_T 14.4269504089f   // 10 * log2(e)

#define AS1 __attribute__((address_space(1)))
#define AS3 __attribute__((address_space(3)))

typedef _Float16 f16x8 __attribute__((ext_vector_type(8)));
typedef _Float16 f16x2 __attribute__((ext_vector_type(2)));
typedef float f32x4 __attribute__((ext_vector_type(4)));

// guard-free 2^x: args are in [-29, 0], no denorm/overflow concerns
__device__ __forceinline__ float ex2(float x) {
#if __has_builtin(__builtin_amdgcn_exp2f)
    return __builtin_amdgcn_exp2f(x);
#else
    return exp2f(x);
#endif
}

// ---- tiny zero: hist (512 ints) + d_out; 1 block, ~1us ----
__global__ __launch_bounds__(256)
void zero_kernel(int* __restrict__ hist, float* __restrict__ out)
{
    hist[threadIdx.x] = 0;
    hist[256 + threadIdx.x] = 0;
    if (threadIdx.x == 0) out[0] = 0.f;
}

// ---- normalize rows -> f16, labels, histogram ----
__global__ __launch_bounds__(256)
void norm_kernel(const float* __restrict__ f, const int* __restrict__ labels,
                 _Float16* __restrict__ fh, int* __restrict__ labm,
                 int* __restrict__ hist, int M, int nrep)
{
    int gw = (blockIdx.x * 256 + threadIdx.x) >> 6;   // one wave per row
    int lane = threadIdx.x & 63;
    if (gw >= M) return;
    float2 v = *reinterpret_cast<const float2*>(&f[(size_t)gw * DD + lane * 2]);
    float ss = v.x * v.x + v.y * v.y;
    #pragma unroll
    for (int m = 1; m < 64; m <<= 1) ss += __shfl_xor(ss, m);
    float inv = 1.0f / fmaxf(sqrtf(ss), 1e-12f);
    f16x2 h; h[0] = (_Float16)(v.x * inv); h[1] = (_Float16)(v.y * inv);
    *reinterpret_cast<f16x2*>(&fh[(size_t)gw * DD + lane * 2]) = h;
    if (lane == 0) {
        int lb = labels[gw / nrep];
        labm[gw] = lb;
        if ((gw % nrep) == 0) atomicAdd(&hist[lb], nrep);  // one atomic per sample
    }
}

// ---- main: f16 MFMA, global_load_lds staging, PAIRED subtile phases ----
// R16 base (4 waves/block, 64 i-rows register-resident, (256,3), LDS DMA
// double-buffer, 32x24 grid = 3 blocks/CU). New: subtiles processed in
// PAIRS per phase -- {ds_read af(k); MFMA->accA; ds_read af(k+1) reusing
// af; MFMA->accB; EPI(accA); EPI(accB)}. accA's MFMA drain is covered by
// af(k+1)'s ds_read + MFMA-B issue; accB's drain by EPI(accA). Session
// regression shows wall time ~ proportional to phase count (~4.8k cyc per
// phase regardless of memory path); pairing halves phases/wave 21->11.
// Liveness: bfr 64 + accA 16 + accB 16 + af 16 transient ~= 140 regs
// (R9's identical shape spilled at ~165 because it also carried the af
// register ping-pong; LDS sourcing removes it). Self-pair subtracted in
// the final kernel.
__global__ __launch_bounds__(256, 3)
void supcon_main(const _Float16* __restrict__ fh, const int* __restrict__ labm,
                 float* __restrict__ Epart, float* __restrict__ Ppart,
                 int M, int nsub_total)
{
    __shared__ float4 jbuf[2][1024];   // 2 x (64 rows x 16 chunks of 16B)

    const int tid = threadIdx.x;
    const int lane = tid & 63;
    const int w = tid >> 6;
    const int ibase = blockIdx.x * 256 + w * 64;
    const int rowsel = lane & 15;
    const int grp = lane >> 4;
    const int ksel = grp * 8;      // f16 k-offset within a 32-wide K step

    // register-resident Fi fragments: 4 subtiles x 4 K-steps = 64 regs
    f16x8 bfr[4][4];
    #pragma unroll
    for (int t = 0; t < 4; ++t)
        #pragma unroll
        for (int kk = 0; kk < 4; ++kk)
            bfr[t][kk] = *reinterpret_cast<const f16x8*>(
                &fh[(size_t)(ibase + t * 16 + rowsel) * DD + kk * 32 + ksel]);

    int li[4];
    #pragma unroll
    for (int t = 0; t < 4; ++t) li[t] = labm[ibase + t * 16 + rowsel];

    float esum[4] = {0.f, 0.f, 0.f, 0.f};
    float psum[4] = {0.f, 0.f, 0.f, 0.f};

    // uneven subtile range for this j-split
    const int base = nsub_total / NSPLIT, rem = nsub_total % NSPLIT;
    const int by = blockIdx.y;
    const int s0 = by * base + (by < rem ? by : rem);
    const int send = s0 + base + (by < rem ? 1 : 0);
    const int nsub = send - s0;          // 21 or 22
    const int nb = (nsub + 3) >> 2;      // 4-subtile batches
    const int rowmax = nsub_total * 16 - 1;

    // staging geometry: wave w, instr p covers LDS slots [(p*4+w)*64, +64);
    // slot s holds global chunk (row = s>>4, c = (s&15) ^ ((s>>4)&7)) so the
    // linear DMA write produces the swizzled layout the reader expects.
    int srow[4], scol[4];
    #pragma unroll
    for (int p = 0; p < 4; ++p) {
        int s = (p * 4 + w) * 64 + lane;
        srow[p] = s >> 4;                          // batch-local row 0..63
        scol[p] = ((s & 15) ^ ((s >> 4) & 7)) * 8; // f16 offset of source chunk
    }

#define STAGE(bb, tt) { \
    const int rb = (s0 + (tt) * 4) * 16; \
    _Pragma("unroll") for (int p = 0; p < 4; ++p) { \
        int rr = rb + srow[p]; if (rr > rowmax) rr = rowmax; \
        const _Float16* gsrc = fh + (size_t)rr * DD + scol[p]; \
        __builtin_amdgcn_global_load_lds((const AS1 void*)gsrc, \
            (AS3 void*)&jbuf[bb][(p * 4 + w) * 64], 16, 0, 0); } }

#define LDSAF(bb, k) { \
    _Pragma("unroll") for (int kk = 0; kk < 4; ++kk) { \
        int slot = ((k) * 16 + rowsel) * 16 + ((kk * 4 + grp) ^ (rowsel & 7)); \
        af[kk] = *reinterpret_cast<const f16x8*>(&jbuf[bb][slot]); } }

#define MFMA16(A, c0, c1, c2, c3) { \
    _Pragma("unroll") for (int kk = 0; kk < 4; ++kk) { \
        c0 = __builtin_amdgcn_mfma_f32_16x16x32_f16(A[kk], bfr[0][kk], c0, 0, 0, 0); \
        c1 = __builtin_amdgcn_mfma_f32_16x16x32_f16(A[kk], bfr[1][kk], c1, 0, 0, 0); \
        c2 = __builtin_amdgcn_mfma_f32_16x16x32_f16(A[kk], bfr[2][kk], c2, 0, 0, 0); \
        c3 = __builtin_amdgcn_mfma_f32_16x16x32_f16(A[kk], bfr[3][kk], c3, 0, 0, 0); } }

#define EPI1(t, cc, L) { \
    esum[t] += (ex2(__builtin_fmaf(cc[0], L2E_T, -L2E_T)) \
              + ex2(__builtin_fmaf(cc[1], L2E_T, -L2E_T))) \
             + (ex2(__builtin_fmaf(cc[2], L2E_T, -L2E_T)) \
              + ex2(__builtin_fmaf(cc[3], L2E_T, -L2E_T))); \
    float p0 = (L.x == li[t]) ? cc[0] : 0.f; \
    float p1 = (L.y == li[t]) ? cc[1] : 0.f; \
    float p2 = (L.z == li[t]) ? cc[2] : 0.f; \
    float p3 = (L.w == li[t]) ? cc[3] : 0.f; \
    psum[t] += (p0 + p1) + (p2 + p3); }

#define EPI4(c0, c1, c2, c3, L) { \
    EPI1(0, c0, L); EPI1(1, c1, L); EPI1(2, c2, L); EPI1(3, c3, L); }

// paired phase: two subtiles k0,k1 of batch tt; af reused (16-reg transient)
#define PAIR(bb, tt, k0, k1) { \
    f16x8 af[4]; \
    LDSAF(bb, k0); \
    f32x4 A0 = {0,0,0,0}, A1 = {0,0,0,0}, A2 = {0,0,0,0}, A3 = {0,0,0,0}; \
    MFMA16(af, A0, A1, A2, A3); \
    LDSAF(bb, k1); \
    f32x4 B0 = {0,0,0,0}, B1 = {0,0,0,0}, B2 = {0,0,0,0}, B3 = {0,0,0,0}; \
    MFMA16(af, B0, B1, B2, B3); \
    const int4 lj0 = *reinterpret_cast<const int4*>( \
        &labm[(s0 + (tt) * 4 + (k0)) * 16 + grp * 4]); \
    const int4 lj1 = *reinterpret_cast<const int4*>( \
        &labm[(s0 + (tt) * 4 + (k1)) * 16 + grp * 4]); \
    EPI4(A0, A1, A2, A3, lj0); \
    EPI4(B0, B1, B2, B3, lj1); }

#define SINGLE(bb, tt, k0) { \
    f16x8 af[4]; \
    LDSAF(bb, k0); \
    f32x4 A0 = {0,0,0,0}, A1 = {0,0,0,0}, A2 = {0,0,0,0}, A3 = {0,0,0,0}; \
    MFMA16(af, A0, A1, A2, A3); \
    const int4 lj0 = *reinterpret_cast<const int4*>( \
        &labm[(s0 + (tt) * 4 + (k0)) * 16 + grp * 4]); \
    EPI4(A0, A1, A2, A3, lj0); }

    STAGE(0, 0);
    __syncthreads();                         // drain batch-0 DMA + barrier
    for (int t = 0; t < nb; ++t) {
        if (t + 1 < nb) STAGE((t + 1) & 1, t + 1);   // DMA next batch
        const int nv = (t == nb - 1) ? (nsub - (nb - 1) * 4) : 4;
        if (nv >= 2) PAIR(t & 1, t, 0, 1);
        if (nv == 4) { PAIR(t & 1, t, 2, 3); }
        else if (nv == 3) { SINGLE(t & 1, t, 2); }
        else if (nv == 1) { SINGLE(t & 1, t, 0); }
        __syncthreads();                     // drain DMA + readers done
    }
#undef STAGE
#undef LDSAF
#undef MFMA16
#undef EPI1
#undef EPI4
#undef PAIR
#undef SINGLE

    // fold lane groups (bits 4,5 = different j rows of the same i)
    #pragma unroll
    for (int t = 0; t < 4; ++t) {
        float e = esum[t], p = psum[t];
        e += __shfl_xor(e, 16); e += __shfl_xor(e, 32);
        p += __shfl_xor(p, 16); p += __shfl_xor(p, 32);
        if (lane < 16) {
            size_t o = (size_t)by * M + ibase + t * 16 + lane;
            Epart[o] = e;
            Ppart[o] = p;
        }
    }
}

// ---- per-row loss term: one thread per row, coalesced partial reads,
// block-reduce, one atomic per block ----
__global__ __launch_bounds__(256)
void final_fused(const _Float16* __restrict__ fh, const float* __restrict__ Epart,
                 const float* __restrict__ Ppart, const int* __restrict__ labm,
                 const int* __restrict__ hist, float* __restrict__ out, int M)
{
    __shared__ float red[4];
    const int i = blockIdx.x * 256 + threadIdx.x;   // one row per thread
    float aii = 0.f;
    const f16x8* fr = reinterpret_cast<const f16x8*>(&fh[(size_t)i * DD]);
    #pragma unroll
    for (int k = 0; k < 16; ++k) {
        f16x8 hv = fr[k];
        #pragma unroll
        for (int e = 0; e < 8; ++e) {
            float x = (float)hv[e];
            aii = __builtin_fmaf(x, x, aii);
        }
    }
    float E = 0.f, P = 0.f;
    #pragma unroll
    for (int k = 0; k < NSPLIT; ++k) {
        E += Epart[(size_t)k * M + i];
        P += Ppart[(size_t)k * M + i];
    }
    int lb = labm[i];
    float cnt = (float)(hist[lb] - 1);
    E -= ex2(__builtin_fmaf(aii, L2E_T, -L2E_T));   // drop self exp
    float term = (SHIFT + logf(E)) - SHIFT * (P - aii) / cnt;

    #pragma unroll
    for (int m = 1; m < 64; m <<= 1) term += __shfl_xor(term, m);
    int lane = threadIdx.x & 63, wv = threadIdx.x >> 6;
    if (lane == 0) red[wv] = term;
    __syncthreads();
    if (threadIdx.x == 0)
        atomicAdd(out, (red[0] + red[1] + red[2] + red[3]) / (float)M);
}

extern "C" void kernel_launch(void* const* d_in, const int* in_sizes, int n_in,
                              void* d_out, int out_size, void* d_ws, size_t ws_size,
                              hipStream_t stream)
{
    const float* feats = (const float*)d_in[0];
    const int* labels = (const int*)d_in[1];
    const int Bn = in_sizes[1];
    const int M = in_sizes[0] / DD;    // 8192
    const int nrep = M / Bn;           // 2

    char* ws = (char*)d_ws;
    _Float16* fh = (_Float16*)ws;
    size_t off = (size_t)M * DD * sizeof(_Float16);
    int* labm = (int*)(ws + off); off += (size_t)M * sizeof(int);
    int* hist = (int*)(ws + off); off += (size_t)NBINS * sizeof(int);
    off = (off + 255) & ~(size_t)255;
    float* Epart = (float*)(ws + off); off += (size_t)NSPLIT * M * sizeof(float);
    float* Ppart = (float*)(ws + off); off += (size_t)NSPLIT * M * sizeof(float);

    zero_kernel<<<1, 256, 0, stream>>>(hist, (float*)d_out);

    norm_kernel<<<M / 4, 256, 0, stream>>>(feats, labels, fh, labm, hist, M, nrep);

    const int nsub_total = M / 16;     // 512 j-subtiles split unevenly over 24
    dim3 grid(M / 256, NSPLIT);        // 32 x 24 = 768 blocks (3/CU, 1 round)
    supcon_main<<<grid, 256, 0, stream>>>(fh, labm, Epart, Ppart, M, nsub_total);

    final_fused<<<M / 256, 256, 0, stream>>>(fh, Epart, Ppart, labm, hist,
                                             (float*)d_out, M);
}